// Round 1
// baseline (273.683 us; speedup 1.0000x reference)
//
#include <hip/hip_runtime.h>

#define NINV 0xFFFFFFFFu
static constexpr int D = 64, H = 64, W = 64;
static constexpr int NVOX = D * H * W;

// ---------------- phase 1: union-find CCL (6-connectivity) ----------------

__global__ void init_parent_k(const float* __restrict__ x, unsigned* __restrict__ parent) {
    int i = blockIdx.x * blockDim.x + threadIdx.x;
    if (i < NVOX) parent[i] = (x[i] > 0.5f) ? (unsigned)i : NINV;
}

__device__ __forceinline__ unsigned find_root(unsigned* parent, unsigned i) {
    unsigned p = parent[i];
    while (p != i) { i = p; p = parent[i]; }
    return i;
}

__device__ void unite(unsigned* parent, unsigned a, unsigned b) {
    for (;;) {
        a = find_root(parent, a);
        b = find_root(parent, b);
        if (a == b) return;
        if (a > b) { unsigned t = a; a = b; b = t; }
        unsigned old = atomicCAS(&parent[b], b, a);
        if (old == b || old == a) return;
        b = old;  // parent[b] changed under us; continue from the observed value
    }
}

__global__ void union_k(unsigned* parent) {
    int i = blockIdx.x * blockDim.x + threadIdx.x;
    if (i >= NVOX) return;
    if (parent[i] == NINV) return;
    int x = i & (W - 1);
    int y = (i >> 6) & (H - 1);
    int z = i >> 12;
    if (x + 1 < W && parent[i + 1]    != NINV) unite(parent, i, i + 1);
    if (y + 1 < H && parent[i + W]    != NINV) unite(parent, i, i + W);
    if (z + 1 < D && parent[i + W*H]  != NINV) unite(parent, i, i + W*H);
}

__global__ void flatten_k(unsigned* parent) {
    int i = blockIdx.x * blockDim.x + threadIdx.x;
    if (i >= NVOX) return;
    unsigned p = parent[i];
    if (p == NINV) return;
    unsigned r = p;
    unsigned q = parent[r];
    while (q != r) { r = q; q = parent[r]; }  // values only decrease: terminates at true root
    parent[i] = r;
}

// ---------------- phase 2: per-voxel topology + weighted BCE ----------------

__device__ __forceinline__ int count_components(unsigned mask, const unsigned* adj) {
    int count = 0;
    while (mask) {
        unsigned comp = mask & (0u - mask);  // lowest set bit as seed
        for (;;) {
            unsigned acc = comp;
            unsigned t = comp;
            while (t) {
                int b = __ffs(t) - 1;
                acc |= adj[b];
                t &= t - 1;
            }
            acc &= mask;
            if (acc == comp) break;
            comp = acc;
        }
        mask &= ~comp;
        ++count;
    }
    return count;
}

__device__ __forceinline__ float weight_for(int i, int x, int y, int z,
                                            const unsigned* __restrict__ lab,
                                            const unsigned* sA18, const unsigned* sA26) {
    unsigned c = lab[i];
    if (c == NINV) return 1.0f;  // background center: ns = 0
    unsigned same = 0;
    int k = 0;
    #pragma unroll
    for (int dz = -1; dz <= 1; ++dz) {
        int zz = z + dz; zz = zz < 0 ? 0 : (zz > D - 1 ? D - 1 : zz);
        #pragma unroll
        for (int dy = -1; dy <= 1; ++dy) {
            int yy = y + dy; yy = yy < 0 ? 0 : (yy > H - 1 ? H - 1 : yy);
            int base = (zz << 12) + (yy << 6);
            #pragma unroll
            for (int dx = -1; dx <= 1; ++dx) {
                int xx = x + dx; xx = xx < 0 ? 0 : (xx > W - 1 ? W - 1 : xx);
                same |= (lab[base + xx] == c ? 1u : 0u) << k;
                ++k;
            }
        }
    }
    unsigned mask1 = (~same) & 0x07FFFFFFu;   // cells with label != center (incl. bg)
    unsigned mask2 = same & ~(1u << 13);      // same-component cells, center excluded
    int c1 = count_components(mask1, sA18);
    int c2 = count_components(mask2, sA26);
    return ((c1 != 1) || (c2 != 1)) ? 10.0f : 1.0f;
}

__global__ void final_k(const float* __restrict__ pred, const float* __restrict__ target,
                        const unsigned* __restrict__ labP, const unsigned* __restrict__ labT,
                        float* __restrict__ out) {
    __shared__ unsigned sA18[27], sA26[27];
    if (threadIdx.x < 27) {
        int ii = threadIdx.x;
        int iz = ii / 9, iy = (ii / 3) % 3, ix = ii % 3;
        unsigned m18 = 0, m26 = 0;
        for (int j = 0; j < 27; ++j) {
            int jz = j / 9, jy = (j / 3) % 3, jx = j % 3;
            int az = iz - jz; az = az < 0 ? -az : az;
            int ay = iy - jy; ay = ay < 0 ? -ay : ay;
            int ax = ix - jx; ax = ax < 0 ? -ax : ax;
            if (az + ay + ax <= 2) m18 |= 1u << j;
            if (az <= 1 && ay <= 1 && ax <= 1) m26 |= 1u << j;
        }
        sA18[ii] = m18; sA26[ii] = m26;
    }
    __syncthreads();

    int i = blockIdx.x * blockDim.x + threadIdx.x;
    float err = 0.0f;
    if (i < NVOX) {
        int x = i & (W - 1);
        int y = (i >> 6) & (H - 1);
        int z = i >> 12;
        float wP = weight_for(i, x, y, z, labP, sA18, sA26);
        float wT = weight_for(i, x, y, z, labT, sA18, sA26);
        float wp = wP * pred[i];
        float wl = wT * target[i];
        float l1pe = log1pf(expf(-fabsf(wp)));
        float sp_pos = fmaxf(wp, 0.0f) + l1pe;   // softplus(wp)
        float sp_neg = fmaxf(-wp, 0.0f) + l1pe;  // softplus(-wp)
        err = wl * sp_neg + (1.0f - wl) * sp_pos;
    }

    // block reduction: wave shuffle -> LDS -> one atomic per block
    #pragma unroll
    for (int o = 32; o > 0; o >>= 1) err += __shfl_down(err, o, 64);
    __shared__ float sred[4];
    int lane = threadIdx.x & 63;
    int wv = threadIdx.x >> 6;
    if (lane == 0) sred[wv] = err;
    __syncthreads();
    if (threadIdx.x == 0) {
        atomicAdd(out, sred[0] + sred[1] + sred[2] + sred[3]);
    }
}

// ---------------- launch ----------------

extern "C" void kernel_launch(void* const* d_in, const int* in_sizes, int n_in,
                              void* d_out, int out_size, void* d_ws, size_t ws_size,
                              hipStream_t stream) {
    const float* pred   = (const float*)d_in[0];
    const float* target = (const float*)d_in[1];
    float* out = (float*)d_out;
    unsigned* parentP = (unsigned*)d_ws;
    unsigned* parentT = parentP + NVOX;

    hipMemsetAsync(d_out, 0, sizeof(float), stream);

    const int blk = 256;
    const int grd = (NVOX + blk - 1) / blk;
    init_parent_k<<<grd, blk, 0, stream>>>(pred, parentP);
    init_parent_k<<<grd, blk, 0, stream>>>(target, parentT);
    union_k<<<grd, blk, 0, stream>>>(parentP);
    union_k<<<grd, blk, 0, stream>>>(parentT);
    flatten_k<<<grd, blk, 0, stream>>>(parentP);
    flatten_k<<<grd, blk, 0, stream>>>(parentT);
    final_k<<<grd, blk, 0, stream>>>(pred, target, parentP, parentT, out);
}

// Round 3
// 142.111 us; speedup vs baseline: 1.9258x; 1.9258x over previous
//
#include <hip/hip_runtime.h>

#define NINV 0xFFFFFFFFu
static constexpr int D = 64, H = 64, W = 64;
static constexpr int NVOX = D * H * W;      // 262144
static constexpr int NTOT = 2 * NVOX;       // both volumes, contiguous in ws

// ---------- global union-find primitives (round-1 proven) ----------

__device__ __forceinline__ unsigned find_root(const unsigned* __restrict__ P, unsigned i) {
    unsigned p = P[i];
    while (p != i) { i = p; p = P[i]; }
    return i;
}

__device__ void unite(unsigned* P, unsigned a, unsigned b) {
    for (;;) {
        a = find_root(P, a);
        b = find_root(P, b);
        if (a == b) return;
        if (a > b) { unsigned t = a; a = b; b = t; }
        unsigned old = atomicCAS(&P[b], b, a);
        if (old == b || old == a) return;
        b = old;  // observed newer (smaller) ancestor; retry from it
    }
}

// ---------- phase 1a: local CCL per 8x8x8 tile, atomic-free LDS min-propagation ----------
// grid: 1024 blocks (512 per volume), 512 threads. Writes depth<=1 global trees
// rooted at the per-tile-component minimum voxel (global index incl. vol offset).

__global__ __launch_bounds__(512) void local_ccl_k(const float* __restrict__ pred,
                                                   const float* __restrict__ target,
                                                   unsigned* __restrict__ parent) {
    __shared__ unsigned lab[512];
    __shared__ int changed;
    int tb  = blockIdx.x & 511;
    int vol = blockIdx.x >> 9;
    const float* src = vol ? target : pred;
    int tx = (tb & 7) << 3;
    int ty = ((tb >> 3) & 7) << 3;
    int tz = (tb >> 6) << 3;

    int l = threadIdx.x;
    int lx = l & 7, ly = (l >> 3) & 7, lz = l >> 6;
    int g = ((tz + lz) << 12) + ((ty + ly) << 6) + (tx + lx);

    bool fg = src[g] > 0.5f;
    lab[l] = fg ? (unsigned)l : NINV;
    __syncthreads();

    for (;;) {
        if (l == 0) changed = 0;
        __syncthreads();
        if (fg) {
            unsigned m = lab[l];                 // bg neighbors hold NINV -> min no-op
            if (lx > 0) m = min(m, lab[l - 1]);
            if (lx < 7) m = min(m, lab[l + 1]);
            if (ly > 0) m = min(m, lab[l - 8]);
            if (ly < 7) m = min(m, lab[l + 8]);
            if (lz > 0) m = min(m, lab[l - 64]);
            if (lz < 7) m = min(m, lab[l + 64]);
            if (m < lab[l]) { lab[l] = m; changed = 1; }  // benign race: labels only decrease
        }
        __syncthreads();
        int done = (changed == 0);
        __syncthreads();          // all read `changed` before anyone resets it next iter
        if (done) break;
    }

    unsigned r = NINV;
    if (fg) {
        unsigned rr = lab[l];     // per-tile-component min local index
        r = (unsigned)(vol * NVOX)
          + (unsigned)(((tz + (int)(rr >> 6)) << 12)
                     + ((ty + (int)((rr >> 3) & 7)) << 6)
                     +  (tx + (int)(rr & 7)));
    }
    parent[vol * NVOX + g] = r;
}

// ---------- phase 1b: merge across tile faces (global union-find) ----------

__global__ void merge_k(unsigned* __restrict__ parent) {
    int i = blockIdx.x * blockDim.x + threadIdx.x;
    if (i >= NTOT) return;
    if (parent[i] == NINV) return;
    int j = i & (NVOX - 1);
    int x = j & 63, y = (j >> 6) & 63, z = j >> 12;
    if ((x & 7) == 7 && x < 63 && parent[i + 1]    != NINV) unite(parent, i, i + 1);
    if ((y & 7) == 7 && y < 63 && parent[i + 64]   != NINV) unite(parent, i, i + 64);
    if ((z & 7) == 7 && z < 63 && parent[i + 4096] != NINV) unite(parent, i, i + 4096);
}

// ---------- phase 1c: full flatten ----------

__global__ void flatten_k(unsigned* __restrict__ parent) {
    int i = blockIdx.x * blockDim.x + threadIdx.x;
    if (i >= NTOT) return;
    unsigned p = parent[i];
    if (p == NINV) return;
    unsigned r = p, q;
    while ((q = parent[r]) != r) r = q;
    parent[i] = r;
}

// ---------- phase 2: per-voxel topology masks + weighted BCE + reduce ----------

__device__ __forceinline__ int count_components(unsigned mask, const unsigned* adj) {
    int count = 0;
    while (mask) {
        unsigned comp = mask & (0u - mask);
        for (;;) {
            unsigned acc = comp;
            unsigned t = comp;
            while (t) {
                int b = __ffs(t) - 1;
                acc |= adj[b];
                t &= t - 1;
            }
            acc &= mask;
            if (acc == comp) break;
            comp = acc;
        }
        mask &= ~comp;
        ++count;
    }
    return count;
}

__device__ __forceinline__ float weight_for(int i, int x, int y, int z,
                                            const unsigned* __restrict__ lab,
                                            const unsigned* sA18, const unsigned* sA26) {
    unsigned c = lab[i];
    if (c == NINV) return 1.0f;
    unsigned same = 0;
    int k = 0;
    #pragma unroll
    for (int dz = -1; dz <= 1; ++dz) {
        int zz = z + dz; zz = zz < 0 ? 0 : (zz > D - 1 ? D - 1 : zz);
        #pragma unroll
        for (int dy = -1; dy <= 1; ++dy) {
            int yy = y + dy; yy = yy < 0 ? 0 : (yy > H - 1 ? H - 1 : yy);
            int base = (zz << 12) + (yy << 6);
            #pragma unroll
            for (int dx = -1; dx <= 1; ++dx) {
                int xx = x + dx; xx = xx < 0 ? 0 : (xx > W - 1 ? W - 1 : xx);
                same |= (lab[base + xx] == c ? 1u : 0u) << k;
                ++k;
            }
        }
    }
    unsigned mask1 = (~same) & 0x07FFFFFFu;
    unsigned mask2 = same & ~(1u << 13);
    int c1 = count_components(mask1, sA18);
    int c2 = count_components(mask2, sA26);
    return ((c1 != 1) || (c2 != 1)) ? 10.0f : 1.0f;
}

__global__ void final_k(const float* __restrict__ pred, const float* __restrict__ target,
                        const unsigned* __restrict__ labP, const unsigned* __restrict__ labT,
                        float* __restrict__ out) {
    __shared__ unsigned sA18[27], sA26[27];
    if (threadIdx.x < 27) {
        int ii = threadIdx.x;
        int iz = ii / 9, iy = (ii / 3) % 3, ix = ii % 3;
        unsigned m18 = 0, m26 = 0;
        for (int j = 0; j < 27; ++j) {
            int jz = j / 9, jy = (j / 3) % 3, jx = j % 3;
            int az = iz - jz; az = az < 0 ? -az : az;
            int ay = iy - jy; ay = ay < 0 ? -ay : ay;
            int ax = ix - jx; ax = ax < 0 ? -ax : ax;
            if (az + ay + ax <= 2) m18 |= 1u << j;
            if (az <= 1 && ay <= 1 && ax <= 1) m26 |= 1u << j;
        }
        sA18[ii] = m18; sA26[ii] = m26;
    }
    __syncthreads();

    int i = blockIdx.x * blockDim.x + threadIdx.x;
    float err = 0.0f;
    if (i < NVOX) {
        int x = i & (W - 1);
        int y = (i >> 6) & (H - 1);
        int z = i >> 12;
        float wP = weight_for(i, x, y, z, labP, sA18, sA26);
        float wT = weight_for(i, x, y, z, labT, sA18, sA26);
        float wp = wP * pred[i];
        float wl = wT * target[i];
        float l1pe = log1pf(expf(-fabsf(wp)));
        float sp_pos = fmaxf(wp, 0.0f) + l1pe;
        float sp_neg = fmaxf(-wp, 0.0f) + l1pe;
        err = wl * sp_neg + (1.0f - wl) * sp_pos;
    }

    #pragma unroll
    for (int o = 32; o > 0; o >>= 1) err += __shfl_down(err, o, 64);
    __shared__ float sred[4];
    int lane = threadIdx.x & 63;
    int wv = threadIdx.x >> 6;
    if (lane == 0) sred[wv] = err;
    __syncthreads();
    if (threadIdx.x == 0) {
        atomicAdd(out, sred[0] + sred[1] + sred[2] + sred[3]);
    }
}

// ---------------- launch ----------------

extern "C" void kernel_launch(void* const* d_in, const int* in_sizes, int n_in,
                              void* d_out, int out_size, void* d_ws, size_t ws_size,
                              hipStream_t stream) {
    const float* pred   = (const float*)d_in[0];
    const float* target = (const float*)d_in[1];
    float* out = (float*)d_out;
    unsigned* parent = (unsigned*)d_ws;          // [2*NVOX]: pred forest, then target forest

    hipMemsetAsync(d_out, 0, sizeof(float), stream);

    local_ccl_k<<<1024, 512, 0, stream>>>(pred, target, parent);
    merge_k<<<NTOT / 256, 256, 0, stream>>>(parent);
    flatten_k<<<NTOT / 256, 256, 0, stream>>>(parent);
    final_k<<<NVOX / 256, 256, 0, stream>>>(pred, target,
                                            parent, parent + NVOX, out);
}

// Round 4
// 130.867 us; speedup vs baseline: 2.0913x; 1.0859x over previous
//
#include <hip/hip_runtime.h>

#define NINV 0xFFFFFFFFu
static constexpr int D = 64, H = 64, W = 64;
static constexpr int NVOX = D * H * W;      // 262144
static constexpr int NTOT = 2 * NVOX;       // both volumes, contiguous in ws

// ---------- global union-find primitives (min-index linking, path halving) ----------
// Halving safety: stores only to permanently-non-root nodes, always stores an
// ancestor (trees only merge, ancestor sets only grow), walk indices strictly
// decrease -> termination. CAS linking only ever targets current roots.

__device__ __forceinline__ unsigned find_c(unsigned* P, unsigned i) {
    unsigned p = P[i];
    while (p != i) {
        unsigned gp = P[p];
        if (gp == p) return p;
        P[i] = gp;          // path halving (benign: gp is an ancestor of i)
        i = gp;
        p = P[i];
    }
    return i;
}

__device__ void unite(unsigned* P, unsigned a, unsigned b) {
    for (;;) {
        a = find_c(P, a);
        b = find_c(P, b);
        if (a == b) return;
        if (a > b) { unsigned t = a; a = b; b = t; }
        unsigned old = atomicCAS(&P[b], b, a);
        if (old == b || old == a) return;
        b = old;  // observed a newer (smaller) ancestor; retry from it
    }
}

// ---------- phase 1a: local CCL per 8x8x8 tile in LDS ----------
// Min-propagation with label chasing (pointer jumping). Single writer per cell
// (own thread) -> no write races; cross-reads are benign (labels only decrease).
// One __syncthreads_count per iteration: if no own-cell changed in an interval,
// no stores happened in it, so all reads saw a consistent fixpoint.

__global__ __launch_bounds__(512) void local_ccl_k(const float* __restrict__ pred,
                                                   const float* __restrict__ target,
                                                   unsigned* __restrict__ parent) {
    __shared__ unsigned lab[512];
    int tb  = blockIdx.x & 511;
    int vol = blockIdx.x >> 9;
    const float* src = vol ? target : pred;
    int tx = (tb & 7) << 3;
    int ty = ((tb >> 3) & 7) << 3;
    int tz = (tb >> 6) << 3;

    int l = threadIdx.x;
    int lx = l & 7, ly = (l >> 3) & 7, lz = l >> 6;
    int g = ((tz + lz) << 12) + ((ty + ly) << 6) + (tx + lx);

    bool fg = src[g] > 0.5f;
    lab[l] = fg ? (unsigned)l : NINV;
    __syncthreads();

    for (;;) {
        int my_changed = 0;
        if (fg) {
            unsigned cur = lab[l];
            unsigned m = cur;                    // bg neighbors hold NINV -> min no-op
            if (lx > 0) m = min(m, lab[l - 1]);
            if (lx < 7) m = min(m, lab[l + 1]);
            if (ly > 0) m = min(m, lab[l - 8]);
            if (ly < 7) m = min(m, lab[l + 8]);
            if (lz > 0) m = min(m, lab[l - 64]);
            if (lz < 7) m = min(m, lab[l + 64]);
            // chase: labels are local indices -> pointer-jump while decreasing
            for (;;) { unsigned p = lab[m]; if (p >= m) break; m = p; }
            if (m < cur) { lab[l] = m; my_changed = 1; }
        }
        if (__syncthreads_count(my_changed) == 0) break;
    }

    unsigned r = NINV;
    if (fg) {
        unsigned rr = lab[l];     // per-tile-component min local index
        r = (unsigned)(vol * NVOX)
          + (unsigned)(((tz + (int)(rr >> 6)) << 12)
                     + ((ty + (int)((rr >> 3) & 7)) << 6)
                     +  (tx + (int)(rr & 7)));
    }
    parent[vol * NVOX + g] = r;
}

// ---------- phase 1b: merge across tile faces (boundary edges only) ----------

static constexpr int FACE_PER_DIR = 7 * 64 * 64;        // 28672
static constexpr int FACE_PER_VOL = 3 * FACE_PER_DIR;   // 86016
static constexpr int FACE_TOT     = 2 * FACE_PER_VOL;   // 172032

__global__ void merge_k(unsigned* __restrict__ parent) {
    int t = blockIdx.x * blockDim.x + threadIdx.x;
    if (t >= FACE_TOT) return;
    int vol = t / FACE_PER_VOL;
    int r   = t - vol * FACE_PER_VOL;
    int dir = r / FACE_PER_DIR;
    int s   = r - dir * FACE_PER_DIR;
    int plane = s >> 12;          // 0..6
    int q     = s & 4095;
    int x, y, z, stride;
    if (dir == 0)      { x = plane * 8 + 7; y = q & 63; z = q >> 6; stride = 1; }
    else if (dir == 1) { y = plane * 8 + 7; x = q & 63; z = q >> 6; stride = 64; }
    else               { z = plane * 8 + 7; x = q & 63; y = q >> 6; stride = 4096; }
    int i = vol * NVOX + (z << 12) + (y << 6) + x;
    if (parent[i] == NINV || parent[i + stride] == NINV) return;
    unite(parent, (unsigned)i, (unsigned)(i + stride));
}

// ---------- phase 1c: full flatten ----------

__global__ void flatten_k(unsigned* __restrict__ parent) {
    int i = blockIdx.x * blockDim.x + threadIdx.x;
    if (i >= NTOT) return;
    unsigned p = parent[i];
    if (p == NINV) return;
    unsigned r = p, q;
    while ((q = parent[r]) != r) r = q;
    parent[i] = r;
}

// ---------- phase 2: per-voxel topology masks + weighted BCE + reduce ----------

__device__ __forceinline__ int count_components(unsigned mask, const unsigned* adj) {
    int count = 0;
    while (mask) {
        unsigned comp = mask & (0u - mask);
        for (;;) {
            unsigned acc = comp;
            unsigned t = comp;
            while (t) {
                int b = __ffs(t) - 1;
                acc |= adj[b];
                t &= t - 1;
            }
            acc &= mask;
            if (acc == comp) break;
            comp = acc;
        }
        mask &= ~comp;
        ++count;
    }
    return count;
}

__device__ __forceinline__ float weight_for(int i, int x, int y, int z,
                                            const unsigned* __restrict__ lab,
                                            const unsigned* sA18, const unsigned* sA26) {
    unsigned c = lab[i];
    if (c == NINV) return 1.0f;
    unsigned same = 0;
    int k = 0;
    #pragma unroll
    for (int dz = -1; dz <= 1; ++dz) {
        int zz = z + dz; zz = zz < 0 ? 0 : (zz > D - 1 ? D - 1 : zz);
        #pragma unroll
        for (int dy = -1; dy <= 1; ++dy) {
            int yy = y + dy; yy = yy < 0 ? 0 : (yy > H - 1 ? H - 1 : yy);
            int base = (zz << 12) + (yy << 6);
            #pragma unroll
            for (int dx = -1; dx <= 1; ++dx) {
                int xx = x + dx; xx = xx < 0 ? 0 : (xx > W - 1 ? W - 1 : xx);
                same |= (lab[base + xx] == c ? 1u : 0u) << k;
                ++k;
            }
        }
    }
    unsigned mask1 = (~same) & 0x07FFFFFFu;
    unsigned mask2 = same & ~(1u << 13);
    int c1 = count_components(mask1, sA18);
    int c2 = count_components(mask2, sA26);
    return ((c1 != 1) || (c2 != 1)) ? 10.0f : 1.0f;
}

__global__ void final_k(const float* __restrict__ pred, const float* __restrict__ target,
                        const unsigned* __restrict__ labP, const unsigned* __restrict__ labT,
                        float* __restrict__ out) {
    __shared__ unsigned sA18[27], sA26[27];
    if (threadIdx.x < 27) {
        int ii = threadIdx.x;
        int iz = ii / 9, iy = (ii / 3) % 3, ix = ii % 3;
        unsigned m18 = 0, m26 = 0;
        for (int j = 0; j < 27; ++j) {
            int jz = j / 9, jy = (j / 3) % 3, jx = j % 3;
            int az = iz - jz; az = az < 0 ? -az : az;
            int ay = iy - jy; ay = ay < 0 ? -ay : ay;
            int ax = ix - jx; ax = ax < 0 ? -ax : ax;
            if (az + ay + ax <= 2) m18 |= 1u << j;
            if (az <= 1 && ay <= 1 && ax <= 1) m26 |= 1u << j;
        }
        sA18[ii] = m18; sA26[ii] = m26;
    }
    __syncthreads();

    int i = blockIdx.x * blockDim.x + threadIdx.x;
    float err = 0.0f;
    if (i < NVOX) {
        int x = i & (W - 1);
        int y = (i >> 6) & (H - 1);
        int z = i >> 12;
        float wP = weight_for(i, x, y, z, labP, sA18, sA26);
        float wT = weight_for(i, x, y, z, labT, sA18, sA26);
        float wp = wP * pred[i];
        float wl = wT * target[i];
        float l1pe = log1pf(expf(-fabsf(wp)));
        float sp_pos = fmaxf(wp, 0.0f) + l1pe;
        float sp_neg = fmaxf(-wp, 0.0f) + l1pe;
        err = wl * sp_neg + (1.0f - wl) * sp_pos;
    }

    #pragma unroll
    for (int o = 32; o > 0; o >>= 1) err += __shfl_down(err, o, 64);
    __shared__ float sred[4];
    int lane = threadIdx.x & 63;
    int wv = threadIdx.x >> 6;
    if (lane == 0) sred[wv] = err;
    __syncthreads();
    if (threadIdx.x == 0) {
        atomicAdd(out, sred[0] + sred[1] + sred[2] + sred[3]);
    }
}

// ---------------- launch ----------------

extern "C" void kernel_launch(void* const* d_in, const int* in_sizes, int n_in,
                              void* d_out, int out_size, void* d_ws, size_t ws_size,
                              hipStream_t stream) {
    const float* pred   = (const float*)d_in[0];
    const float* target = (const float*)d_in[1];
    float* out = (float*)d_out;
    unsigned* parent = (unsigned*)d_ws;          // [2*NVOX]: pred forest, then target forest

    hipMemsetAsync(d_out, 0, sizeof(float), stream);

    local_ccl_k<<<1024, 512, 0, stream>>>(pred, target, parent);
    merge_k<<<(FACE_TOT + 255) / 256, 256, 0, stream>>>(parent);
    flatten_k<<<NTOT / 256, 256, 0, stream>>>(parent);
    final_k<<<NVOX / 256, 256, 0, stream>>>(pred, target,
                                            parent, parent + NVOX, out);
}

// Round 5
// 124.646 us; speedup vs baseline: 2.1957x; 1.0499x over previous
//
#include <hip/hip_runtime.h>

#define NINV 0xFFFFFFFFu
static constexpr int D = 64, H = 64, W = 64;
static constexpr int NVOX = D * H * W;      // 262144
static constexpr int NTOT = 2 * NVOX;       // both volumes, contiguous in ws

// ---------- global union-find primitives (min-index linking, path halving) ----------
// Halving safety: stores only to permanently-non-root nodes, always stores an
// ancestor, walk indices strictly decrease -> termination. CAS only hits roots.
// Leaf entries (plain voxels) are NEVER rewritten: find paths start at tile-roots.

__device__ __forceinline__ unsigned find_c(unsigned* P, unsigned i) {
    unsigned p = P[i];
    while (p != i) {
        unsigned gp = P[p];
        if (gp == p) return p;
        P[i] = gp;          // path halving (benign: gp is an ancestor of i)
        i = gp;
        p = P[i];
    }
    return i;
}

__device__ void unite(unsigned* P, unsigned a, unsigned b) {
    for (;;) {
        a = find_c(P, a);
        b = find_c(P, b);
        if (a == b) return;
        if (a > b) { unsigned t = a; a = b; b = t; }
        unsigned old = atomicCAS(&P[b], b, a);
        if (old == b || old == a) return;
        b = old;  // observed a newer (smaller) ancestor; retry from it
    }
}

// ---------- phase 1a: local CCL per 8x8x8 tile in LDS ----------

__global__ __launch_bounds__(512) void local_ccl_k(const float* __restrict__ pred,
                                                   const float* __restrict__ target,
                                                   unsigned* __restrict__ parent) {
    __shared__ unsigned lab[512];
    int tb  = blockIdx.x & 511;
    int vol = blockIdx.x >> 9;
    const float* src = vol ? target : pred;
    int tx = (tb & 7) << 3;
    int ty = ((tb >> 3) & 7) << 3;
    int tz = (tb >> 6) << 3;

    int l = threadIdx.x;
    int lx = l & 7, ly = (l >> 3) & 7, lz = l >> 6;
    int g = ((tz + lz) << 12) + ((ty + ly) << 6) + (tx + lx);

    bool fg = src[g] > 0.5f;
    lab[l] = fg ? (unsigned)l : NINV;
    __syncthreads();

    for (;;) {
        int my_changed = 0;
        if (fg) {
            unsigned cur = lab[l];
            unsigned m = cur;                    // bg neighbors hold NINV -> min no-op
            if (lx > 0) m = min(m, lab[l - 1]);
            if (lx < 7) m = min(m, lab[l + 1]);
            if (ly > 0) m = min(m, lab[l - 8]);
            if (ly < 7) m = min(m, lab[l + 8]);
            if (lz > 0) m = min(m, lab[l - 64]);
            if (lz < 7) m = min(m, lab[l + 64]);
            for (;;) { unsigned p = lab[m]; if (p >= m) break; m = p; }  // chase
            if (m < cur) { lab[l] = m; my_changed = 1; }
        }
        if (__syncthreads_count(my_changed) == 0) break;
    }

    unsigned r = NINV;
    if (fg) {
        unsigned rr = lab[l];     // per-tile-component min local index
        r = (unsigned)(vol * NVOX)
          + (unsigned)(((tz + (int)(rr >> 6)) << 12)
                     + ((ty + (int)((rr >> 3) & 7)) << 6)
                     +  (tx + (int)(rr & 7)));
    }
    parent[vol * NVOX + g] = r;
}

// ---------- phase 1b: merge across tile faces, one wave per 8x8 tile-face ----------
// In-wave dedup: leaf parent entries are the stable tile-roots, so (ra,rb) is a
// stable key; leader election keeps one unite per distinct pair per face.

static constexpr int FACES_PER_DIR = 7 * 8 * 8;        // 448 tile-faces / dir / vol
static constexpr int FACES_PER_VOL = 3 * FACES_PER_DIR; // 1344
static constexpr int FACES_TOT     = 2 * FACES_PER_VOL; // 2688

__global__ void merge_k(unsigned* __restrict__ parent) {
    int wave = (int)((blockIdx.x * blockDim.x + threadIdx.x) >> 6);
    int lane = threadIdx.x & 63;
    if (wave >= FACES_TOT) return;
    int vol = wave / FACES_PER_VOL;
    int f   = wave - vol * FACES_PER_VOL;
    int dir = f / FACES_PER_DIR;
    int ff  = f - dir * FACES_PER_DIR;
    int plane = ff >> 6;       // 0..6
    int tf    = ff & 63;       // 8x8 tile coords within the face
    int a0 = ((tf & 7) << 3) + (lane & 7);
    int a1 = ((tf >> 3) << 3) + (lane >> 3);
    int x, y, z, stride;
    if (dir == 0)      { x = plane * 8 + 7; y = a0; z = a1; stride = 1; }
    else if (dir == 1) { y = plane * 8 + 7; x = a0; z = a1; stride = 64; }
    else               { z = plane * 8 + 7; x = a0; y = a1; stride = 4096; }
    int i = vol * NVOX + (z << 12) + (y << 6) + x;

    unsigned ra = parent[i];
    unsigned rb = parent[i + stride];
    bool valid = (ra != NINV) && (rb != NINV);
    unsigned long long key = valid ? (((unsigned long long)ra << 32) | rb) : ~0ull;

    bool leader = valid;
    #pragma unroll 8
    for (int j = 0; j < 64; ++j) {
        unsigned long long kj = __shfl(key, j, 64);
        if (j < lane && kj == key) leader = false;
    }
    if (leader) unite(parent, ra, rb);
}

// ---------- phase 1c: full flatten ----------

__global__ void flatten_k(unsigned* __restrict__ parent) {
    int i = blockIdx.x * blockDim.x + threadIdx.x;
    if (i >= NTOT) return;
    unsigned p = parent[i];
    if (p == NINV) return;
    unsigned r = p, q;
    while ((q = parent[r]) != r) r = q;
    parent[i] = r;
}

// ---------- phase 2: per-voxel topology masks + weighted BCE + reduce ----------
// Block = one 8x8x8 tile; 10x10x10 clamped label halos staged in LDS per volume.

__device__ __forceinline__ int count_components(unsigned mask, const unsigned* adj) {
    int count = 0;
    while (mask) {
        unsigned comp = mask & (0u - mask);
        for (;;) {
            unsigned acc = comp;
            unsigned t = comp;
            while (t) {
                int b = __ffs(t) - 1;
                acc |= adj[b];
                t &= t - 1;
            }
            acc &= mask;
            if (acc == comp) break;
            comp = acc;
        }
        mask &= ~comp;
        ++count;
    }
    return count;
}

__device__ __forceinline__ float weight_lds(const unsigned* __restrict__ h,
                                            int lx, int ly, int lz,
                                            const unsigned* sA18, const unsigned* sA26) {
    int ctr = (lz + 1) * 100 + (ly + 1) * 10 + (lx + 1);
    unsigned c = h[ctr];
    if (c == NINV) return 1.0f;
    unsigned same = 0;
    int k = 0;
    #pragma unroll
    for (int dz = 0; dz <= 2; ++dz) {
        #pragma unroll
        for (int dy = 0; dy <= 2; ++dy) {
            int base = (lz + dz) * 100 + (ly + dy) * 10 + lx;
            #pragma unroll
            for (int dx = 0; dx <= 2; ++dx) {
                same |= (h[base + dx] == c ? 1u : 0u) << k;
                ++k;
            }
        }
    }
    unsigned mask1 = (~same) & 0x07FFFFFFu;
    unsigned mask2 = same & ~(1u << 13);
    int c1 = count_components(mask1, sA18);
    int c2 = count_components(mask2, sA26);
    return ((c1 != 1) || (c2 != 1)) ? 10.0f : 1.0f;
}

__global__ __launch_bounds__(512) void final_k(const float* __restrict__ pred,
                                               const float* __restrict__ target,
                                               const unsigned* __restrict__ labP,
                                               const unsigned* __restrict__ labT,
                                               float* __restrict__ out) {
    __shared__ unsigned sA18[27], sA26[27];
    __shared__ unsigned hP[1000], hT[1000];
    __shared__ float sred[8];

    int l = threadIdx.x;
    if (l < 27) {
        int iz = l / 9, iy = (l / 3) % 3, ix = l % 3;
        unsigned m18 = 0, m26 = 0;
        for (int j = 0; j < 27; ++j) {
            int jz = j / 9, jy = (j / 3) % 3, jx = j % 3;
            int az = iz - jz; az = az < 0 ? -az : az;
            int ay = iy - jy; ay = ay < 0 ? -ay : ay;
            int ax = ix - jx; ax = ax < 0 ? -ax : ax;
            if (az + ay + ax <= 2) m18 |= 1u << j;
            if (az <= 1 && ay <= 1 && ax <= 1) m26 |= 1u << j;
        }
        sA18[l] = m18; sA26[l] = m26;
    }

    int tb = blockIdx.x;                 // 512 tiles
    int tx = (tb & 7) << 3;
    int ty = ((tb >> 3) & 7) << 3;
    int tz = (tb >> 6) << 3;

    for (int e = l; e < 1000; e += 512) {
        int hx = e % 10, hy = (e / 10) % 10, hz = e / 100;
        int gx = min(max(tx + hx - 1, 0), 63);
        int gy = min(max(ty + hy - 1, 0), 63);
        int gz = min(max(tz + hz - 1, 0), 63);
        int g = (gz << 12) + (gy << 6) + gx;
        hP[e] = labP[g];
        hT[e] = labT[g];
    }
    __syncthreads();

    int lx = l & 7, ly = (l >> 3) & 7, lz = l >> 6;
    int g = ((tz + lz) << 12) + ((ty + ly) << 6) + (tx + lx);

    float wP = weight_lds(hP, lx, ly, lz, sA18, sA26);
    float wT = weight_lds(hT, lx, ly, lz, sA18, sA26);
    float wp = wP * pred[g];
    float wl = wT * target[g];
    float l1pe = log1pf(expf(-fabsf(wp)));
    float sp_pos = fmaxf(wp, 0.0f) + l1pe;
    float sp_neg = fmaxf(-wp, 0.0f) + l1pe;
    float err = wl * sp_neg + (1.0f - wl) * sp_pos;

    #pragma unroll
    for (int o = 32; o > 0; o >>= 1) err += __shfl_down(err, o, 64);
    int lane = l & 63;
    int wv = l >> 6;
    if (lane == 0) sred[wv] = err;
    __syncthreads();
    if (l == 0) {
        float s = 0.0f;
        #pragma unroll
        for (int w = 0; w < 8; ++w) s += sred[w];
        atomicAdd(out, s);
    }
}

// ---------------- launch ----------------

extern "C" void kernel_launch(void* const* d_in, const int* in_sizes, int n_in,
                              void* d_out, int out_size, void* d_ws, size_t ws_size,
                              hipStream_t stream) {
    const float* pred   = (const float*)d_in[0];
    const float* target = (const float*)d_in[1];
    float* out = (float*)d_out;
    unsigned* parent = (unsigned*)d_ws;          // [2*NVOX]: pred forest, then target forest

    hipMemsetAsync(d_out, 0, sizeof(float), stream);

    local_ccl_k<<<1024, 512, 0, stream>>>(pred, target, parent);
    merge_k<<<FACES_TOT * 64 / 256, 256, 0, stream>>>(parent);
    flatten_k<<<NTOT / 256, 256, 0, stream>>>(parent);
    final_k<<<512, 512, 0, stream>>>(pred, target, parent, parent + NVOX, out);
}

// Round 7
// 111.037 us; speedup vs baseline: 2.4648x; 1.1226x over previous
//
#include <hip/hip_runtime.h>

#define NINV 0xFFFFFFFFu
static constexpr int D = 64, H = 64, W = 64;
static constexpr int NVOX = D * H * W;      // 262144
static constexpr int NTOT = 2 * NVOX;       // both volumes, contiguous in ws

// ---------- global union-find primitives (min-index linking, path halving) ----------

__device__ __forceinline__ unsigned find_c(unsigned* P, unsigned i) {
    unsigned p = P[i];
    while (p != i) {
        unsigned gp = P[p];
        if (gp == p) return p;
        P[i] = gp;          // path halving (benign: gp is an ancestor of i)
        i = gp;
        p = P[i];
    }
    return i;
}

__device__ void unite(unsigned* P, unsigned a, unsigned b) {
    for (;;) {
        a = find_c(P, a);
        b = find_c(P, b);
        if (a == b) return;
        if (a > b) { unsigned t = a; a = b; b = t; }
        unsigned old = atomicCAS(&P[b], b, a);
        if (old == b || old == a) return;
        b = old;
    }
}

// ---------- phase 1a: local CCL per 8x8x8 tile in LDS ----------

__global__ __launch_bounds__(512) void local_ccl_k(const float* __restrict__ pred,
                                                   const float* __restrict__ target,
                                                   unsigned* __restrict__ parent) {
    __shared__ unsigned lab[512];
    int tb  = blockIdx.x & 511;
    int vol = blockIdx.x >> 9;
    const float* src = vol ? target : pred;
    int tx = (tb & 7) << 3;
    int ty = ((tb >> 3) & 7) << 3;
    int tz = (tb >> 6) << 3;

    int l = threadIdx.x;
    int lx = l & 7, ly = (l >> 3) & 7, lz = l >> 6;
    int g = ((tz + lz) << 12) + ((ty + ly) << 6) + (tx + lx);

    bool fg = src[g] > 0.5f;
    lab[l] = fg ? (unsigned)l : NINV;
    __syncthreads();

    for (;;) {
        int my_changed = 0;
        if (fg) {
            unsigned cur = lab[l];
            unsigned m = cur;
            if (lx > 0) m = min(m, lab[l - 1]);
            if (lx < 7) m = min(m, lab[l + 1]);
            if (ly > 0) m = min(m, lab[l - 8]);
            if (ly < 7) m = min(m, lab[l + 8]);
            if (lz > 0) m = min(m, lab[l - 64]);
            if (lz < 7) m = min(m, lab[l + 64]);
            for (;;) { unsigned p = lab[m]; if (p >= m) break; m = p; }  // chase
            if (m < cur) { lab[l] = m; my_changed = 1; }
        }
        if (__syncthreads_count(my_changed) == 0) break;
    }

    unsigned r = NINV;
    if (fg) {
        unsigned rr = lab[l];
        r = (unsigned)(vol * NVOX)
          + (unsigned)(((tz + (int)(rr >> 6)) << 12)
                     + ((ty + (int)((rr >> 3) & 7)) << 6)
                     +  (tx + (int)(rr & 7)));
    }
    parent[vol * NVOX + g] = r;
}

// ---------- phase 1b: merge across tile faces, one wave per 8x8 tile-face ----------

static constexpr int FACES_PER_DIR = 7 * 8 * 8;         // 448
static constexpr int FACES_PER_VOL = 3 * FACES_PER_DIR; // 1344
static constexpr int FACES_TOT     = 2 * FACES_PER_VOL; // 2688

__global__ void merge_k(unsigned* __restrict__ parent) {
    int wave = (int)((blockIdx.x * blockDim.x + threadIdx.x) >> 6);
    int lane = threadIdx.x & 63;
    if (wave >= FACES_TOT) return;
    int vol = wave / FACES_PER_VOL;
    int f   = wave - vol * FACES_PER_VOL;
    int dir = f / FACES_PER_DIR;
    int ff  = f - dir * FACES_PER_DIR;
    int plane = ff >> 6;
    int tf    = ff & 63;
    int a0 = ((tf & 7) << 3) + (lane & 7);
    int a1 = ((tf >> 3) << 3) + (lane >> 3);
    int x, y, z, stride;
    if (dir == 0)      { x = plane * 8 + 7; y = a0; z = a1; stride = 1; }
    else if (dir == 1) { y = plane * 8 + 7; x = a0; z = a1; stride = 64; }
    else               { z = plane * 8 + 7; x = a0; y = a1; stride = 4096; }
    int i = vol * NVOX + (z << 12) + (y << 6) + x;

    unsigned ra = parent[i];
    unsigned rb = parent[i + stride];
    bool valid = (ra != NINV) && (rb != NINV);
    unsigned long long key = valid ? (((unsigned long long)ra << 32) | rb) : ~0ull;

    bool leader = valid;
    #pragma unroll 8
    for (int j = 0; j < 64; ++j) {
        unsigned long long kj = __shfl(key, j, 64);
        if (j < lane && kj == key) leader = false;
    }
    if (leader) unite(parent, ra, rb);
}

// ---------- phase 2: halo-chase + packed-27-bit topology + weighted BCE ----------
// Bit k = dz*9 + dy*3 + dx (dz,dy,dx in 0..2); center = bit 13.
// Reference adjacency is over PAIRS of the 27 positions: diffs range [-2,2].
// A18: L1(diff) <= 2  -> (a) <=2 nonzero +-1 components, AND (b) single +-2 axis.
// A26: Linf(diff) <= 1 -> Chebyshev-1 dilation.

static constexpr unsigned ALL27 = 0x7FFFFFFu;
static constexpr unsigned XL2 = 0x36DB6DBu;  // x<2 (can shift +1)
static constexpr unsigned XG0 = 0x6DB6DB6u;  // x>0 (can shift -1)
static constexpr unsigned YL2 = 0x0FC7E3Fu;  // y<2
static constexpr unsigned YG0 = 0x7E3F1F8u;  // y>0
static constexpr unsigned ZL2 = 0x003FFFFu;  // z<2
static constexpr unsigned ZG0 = 0x7FFFE00u;  // z>0
static constexpr unsigned X0  = 0x1249249u;  // x==0
static constexpr unsigned X2  = 0x4924924u;  // x==2
static constexpr unsigned Y0  = 0x01C0E07u;  // y==0
static constexpr unsigned Y2  = 0x70381C0u;  // y==2
static constexpr unsigned Z0  = 0x00001FFu;  // z==0
static constexpr unsigned Z2  = 0x7FC0000u;  // z==2

__device__ __forceinline__ unsigned dilX(unsigned m) {
    return m | ((m & XL2) << 1) | ((m & XG0) >> 1);
}
__device__ __forceinline__ unsigned dilY(unsigned m) {
    return m | ((m & YL2) << 3) | ((m & YG0) >> 3);
}
__device__ __forceinline__ unsigned dilZ(unsigned m) {
    return m | ((m & ZL2) << 9) | ((m & ZG0) >> 9);
}
__device__ __forceinline__ unsigned dil2(unsigned m) {   // single-axis +-2 shifts
    return ((m & X0) << 2) | ((m & X2) >> 2)
         | ((m & Y0) << 6) | ((m & Y2) >> 6)
         | ((m & Z0) << 18) | ((m & Z2) >> 18);
}

// true iff #components != 1 (0 components also returns true)
__device__ __forceinline__ bool multi18(unsigned mask) {
    if (mask == 0) return true;
    unsigned comp = mask & (0u - mask);
    for (;;) {
        unsigned a = dilX(comp), b = dilY(comp);
        unsigned n = (dilY(a) | dilZ(a) | dilZ(b) | dil2(comp)) & mask;
        if (n == comp) break;
        comp = n;
    }
    return comp != mask;
}

__device__ __forceinline__ bool multi26(unsigned mask) {
    if (mask == 0) return true;
    unsigned comp = mask & (0u - mask);
    for (;;) {
        unsigned n = dilZ(dilY(dilX(comp))) & mask;
        if (n == comp) break;
        comp = n;
    }
    return comp != mask;
}

__device__ __forceinline__ float weight_lds(const unsigned* __restrict__ h,
                                            int lx, int ly, int lz) {
    int ctr = (lz + 1) * 100 + (ly + 1) * 10 + (lx + 1);
    unsigned c = h[ctr];
    if (c == NINV) return 1.0f;          // background center: simple
    unsigned same = 0;
    int k = 0;
    #pragma unroll
    for (int dz = 0; dz <= 2; ++dz) {
        #pragma unroll
        for (int dy = 0; dy <= 2; ++dy) {
            int base = (lz + dz) * 100 + (ly + dy) * 10 + lx;
            #pragma unroll
            for (int dx = 0; dx <= 2; ++dx) {
                same |= (h[base + dx] == c ? 1u : 0u) << k;
                ++k;
            }
        }
    }
    unsigned m1 = (~same) & ALL27;       // label != center (incl. bg), 18-adj test
    unsigned m2 = same & ~(1u << 13);    // same comp minus center, 26-adj test
    bool ns = multi18(m1) || multi26(m2);
    return ns ? 10.0f : 1.0f;
}

__global__ __launch_bounds__(512) void final_k(const float* __restrict__ pred,
                                               const float* __restrict__ target,
                                               unsigned* __restrict__ parent,
                                               float* __restrict__ out) {
    __shared__ unsigned hP[1000], hT[1000];
    __shared__ float sred[8];

    int l = threadIdx.x;
    int tb = blockIdx.x;                 // 512 tiles
    int tx = (tb & 7) << 3;
    int ty = ((tb >> 3) & 7) << 3;
    int tz = (tb >> 6) << 3;

    for (int e = l; e < 1000; e += 512) {
        int hx = e % 10, hy = (e / 10) % 10, hz = e / 100;
        int gx = min(max(tx + hx - 1, 0), 63);
        int gy = min(max(ty + hy - 1, 0), 63);
        int gz = min(max(tz + hz - 1, 0), 63);
        int g = (gz << 12) + (gy << 6) + gx;
        // chase to root (forest is quiescent; chains are short post-merge)
        unsigned p = parent[g];
        if (p != NINV) { unsigned q; while ((q = parent[p]) != p) p = q; }
        hP[e] = p;
        unsigned s = parent[NVOX + g];
        if (s != NINV) { unsigned q; while ((q = parent[s]) != s) s = q; }
        hT[e] = s;
    }
    __syncthreads();

    int lx = l & 7, ly = (l >> 3) & 7, lz = l >> 6;
    int g = ((tz + lz) << 12) + ((ty + ly) << 6) + (tx + lx);

    float wP = weight_lds(hP, lx, ly, lz);
    float wT = weight_lds(hT, lx, ly, lz);
    float wp = wP * pred[g];
    float wl = wT * target[g];
    float l1pe = log1pf(expf(-fabsf(wp)));
    float sp_pos = fmaxf(wp, 0.0f) + l1pe;
    float sp_neg = fmaxf(-wp, 0.0f) + l1pe;
    float err = wl * sp_neg + (1.0f - wl) * sp_pos;

    #pragma unroll
    for (int o = 32; o > 0; o >>= 1) err += __shfl_down(err, o, 64);
    int lane = l & 63;
    int wv = l >> 6;
    if (lane == 0) sred[wv] = err;
    __syncthreads();
    if (l == 0) {
        float s = 0.0f;
        #pragma unroll
        for (int w = 0; w < 8; ++w) s += sred[w];
        atomicAdd(out, s);
    }
}

// ---------------- launch ----------------

extern "C" void kernel_launch(void* const* d_in, const int* in_sizes, int n_in,
                              void* d_out, int out_size, void* d_ws, size_t ws_size,
                              hipStream_t stream) {
    const float* pred   = (const float*)d_in[0];
    const float* target = (const float*)d_in[1];
    float* out = (float*)d_out;
    unsigned* parent = (unsigned*)d_ws;          // [2*NVOX]

    hipMemsetAsync(d_out, 0, sizeof(float), stream);

    local_ccl_k<<<1024, 512, 0, stream>>>(pred, target, parent);
    merge_k<<<FACES_TOT * 64 / 256, 256, 0, stream>>>(parent);
    final_k<<<512, 512, 0, stream>>>(pred, target, parent, out);
}